// Round 13
// baseline (698.595 us; speedup 1.0000x reference)
//
#include <hip/hip_runtime.h>
#include <hip/hip_bf16.h>

#define NN 30000
#define EE 300000
#define BB 64
#define HH 4
#define CC 64
#define HC 256

typedef __attribute__((ext_vector_type(8))) short short8;
typedef __attribute__((ext_vector_type(4))) float floatx4;

__device__ __forceinline__ float b2f(short x) {
    return __uint_as_float(((unsigned)(unsigned short)x) << 16);
}
__device__ __forceinline__ unsigned short f2b(float f) {
    __hip_bfloat16 h = __float2bfloat16(f);
    return *(unsigned short*)&h;
}

#define GLD16(gp, lp) __builtin_amdgcn_global_load_lds( \
    (const __attribute__((address_space(1))) void*)(gp), \
    (__attribute__((address_space(3))) void*)(lp), 16, 0, 0)

#define ROT2(x) ((((x) << 2) | ((x) >> 3)) & 31)
#define EESWZ(chunk, row) (ROT2(chunk) ^ (((row) >> 2) & 3) ^ (((row) & 1) << 2))

// ===================== bf16 MFMA GEMM (dense transforms) =================
template<int CT>
__global__ __launch_bounds__(256) void mfma_gemm(
    const ushort* __restrict__ A, const ushort* __restrict__ Bt,
    const float* __restrict__ bias, float* __restrict__ outF,
    __hip_bfloat16* __restrict__ outB, int M, int Nc, int K) {
    constexpr int SMEM_USHORTS =
        ((64 * 32 + CT * 64 * 32) > (64 * CT * 64)) ? (64 * 32 + CT * 64 * 32)
                                                    : (64 * CT * 64);
    __shared__ __align__(16) ushort smem[SMEM_USHORTS];
    ushort* lA = smem;
    ushort* lB = smem + 64 * 32;
    const int tid = threadIdx.x, lane = tid & 63, wv = tid >> 6;
    const int row0 = blockIdx.x * 64, col0 = blockIdx.y * (CT * 64);

    floatx4 acc[4][CT];
#pragma unroll
    for (int r = 0; r < 4; r++)
#pragma unroll
        for (int c = 0; c < CT; c++) acc[r][c] = (floatx4){0.f, 0.f, 0.f, 0.f};

    const int arow = tid >> 2;
    const int sl   = (tid & 3) ^ ((tid >> 3) & 3);
    const ushort* ga = A + (size_t)(row0 + arow) * K + sl * 8;
    const int m16 = lane & 15, q = lane >> 4;

    for (int k0 = 0; k0 < K; k0 += 32) {
        __syncthreads();
        GLD16(ga + k0, &lA[tid * 8]);
#pragma unroll
        for (int j = 0; j < CT; j++) {
            const ushort* gb = Bt + (size_t)(col0 + j * 64 + arow) * K + k0 + sl * 8;
            GLD16(gb, &lB[j * 2048 + tid * 8]);
        }
        __syncthreads();
        short8 aF[4], bF[CT];
#pragma unroll
        for (int r = 0; r < 4; r++) {
            int rr = r * 16 + m16;
            aF[r] = *(const short8*)&lA[rr * 32 + ((q ^ ((rr >> 1) & 3)) << 3)];
        }
#pragma unroll
        for (int c = 0; c < CT; c++) {
            int nr = (wv * CT + c) * 16 + m16;
            bF[c] = *(const short8*)&lB[nr * 32 + ((q ^ ((nr >> 1) & 3)) << 3)];
        }
#pragma unroll
        for (int r = 0; r < 4; r++)
#pragma unroll
            for (int c = 0; c < CT; c++)
                acc[r][c] = __builtin_amdgcn_mfma_f32_16x16x32_bf16(aF[r], bF[c], acc[r][c], 0, 0, 0);
    }

    if (outB != nullptr) {
        __syncthreads();
#pragma unroll
        for (int c = 0; c < CT; c++) {
            int lcol = (wv * CT + c) * 16 + m16;
            float bv = bias ? bias[col0 + lcol] : 0.f;
            int ch = lcol >> 3, c7 = lcol & 7;
#pragma unroll
            for (int r = 0; r < 4; r++)
#pragma unroll
                for (int j = 0; j < 4; j++) {
                    int row = r * 16 + q * 4 + j;
                    smem[row * (CT * 64) + ((ch ^ (row & 7)) << 3) + c7] =
                        f2b(acc[r][c][j] + bv);
                }
        }
        __syncthreads();
        constexpr int SH = (CT == 4) ? 5 : 4;
#pragma unroll
        for (int s = 0; s < CT * 2; s++) {
            int g = tid + 256 * s;
            int row = g >> SH, ch = g & (CT * 8 - 1);
            int grow = row0 + row;
            if (grow < M) {
                short8 v = *(const short8*)&smem[row * (CT * 64) + ((ch ^ (row & 7)) << 3)];
                *(short8*)((ushort*)outB + (size_t)grow * Nc + col0 + ch * 8) = v;
            }
        }
    } else {
#pragma unroll
        for (int c = 0; c < CT; c++) {
            int col = col0 + (wv * CT + c) * 16 + m16;
            float bv = bias ? bias[col] : 0.f;
#pragma unroll
            for (int r = 0; r < 4; r++)
#pragma unroll
                for (int j = 0; j < 4; j++) {
                    int row = row0 + r * 16 + q * 4 + j;
                    if (row < M) outF[(size_t)row * Nc + col] = acc[r][c][j] + bv;
                }
        }
    }
}

// ===================== ea -> row-contiguous bf16 (CSR order) =============
__global__ void permute_ea_frag(const float* __restrict__ ea,
                                const int* __restrict__ einv,
                                ushort* __restrict__ ea_frag) {
    const int t = blockIdx.x * 256 + threadIdx.x;
    const int e = t >> 3, ch = t & 7;
    if (e >= 300032) return;
    const bool live = e < EE;
    const int p = live ? einv[e] : e;
    short8 v8;
#pragma unroll
    for (int j = 0; j < 8; j++) {
        int k = ch * 8 + j;
        float v = (live && k < 51) ? ea[(size_t)e * 51 + k] : 0.f;
        v8[j] = (short)f2b(v);
    }
    *(short8*)&ea_frag[(size_t)p * 64 + ch * 8] = v8;
}

// ===================== consolidated setup (R13) ==========================
// pack_x + W2t/Wpt packs + we_frag + bcat2 + COMPOSED layer-1 weights:
// Wc = W0@[Wl1|Wr1] (13x512, K padded to 32, B^T layout), bc = b0@[..]+[bl|br].
// Removes the init GEMM dispatch and cuts layer-1 K 128->32.
struct SetupParams {
    const float *x, *W0, *b0, *Wl1, *Wr1, *Wl2, *Wr2, *Wp, *We1, *We2;
    const float *bl1, *br1, *bl2, *br2;
    __hip_bfloat16 *xpad, *W2t, *Wpt;
    ushort *Wef1, *Wef2, *Wct;
    float *bcat2, *bc;
    int *deg;
};
__global__ void setup_all(SetupParams P) {
    const int b = blockIdx.x, t = threadIdx.x;
    if (b < 3750) {                               // pack_x + deg zero
        int i = b * 256 + t;
        if (i < NN) P.deg[i] = 0;
        int n = i >> 5, k = i & 31;
        P.xpad[i] = __float2bfloat16(k < 13 ? P.x[n * 13 + k] : 0.f);
    } else if (b < 4006) {                        // W2t left (Wl2, K=256)
        int o = (b - 3750) * 256 + t;             // < 65536
        int n = o >> 8, k = o & 255;
        P.W2t[(size_t)n * 256 + k] = __float2bfloat16(P.Wl2[k * 256 + n]);
    } else if (b < 4262) {                        // W2t right (Wr2, rowoff 256)
        int o = (b - 4006) * 256 + t;
        int n = o >> 8, k = o & 255;
        P.W2t[(size_t)(256 + n) * 256 + k] = __float2bfloat16(P.Wr2[k * 256 + n]);
    } else if (b < 4518) {                        // Wpt (Wp, K=256)
        int o = (b - 4262) * 256 + t;
        int n = o >> 8, k = o & 255;
        P.Wpt[(size_t)n * 256 + k] = __float2bfloat16(P.Wp[k * 256 + n]);
    } else if (b < 4646) {                        // we_frag (We1 then We2)
        int which = (b - 4518) >> 6;
        int o = ((b - 4518) & 63) * 256 + t;      // < 16384
        const float* We = which ? P.We2 : P.We1;
        ushort* Wf = which ? P.Wef2 : P.Wef1;
        int j = o & 7, m16 = (o >> 3) & 15, ch = (o >> 7) & 7, nt = o >> 10;
        int n = nt * 16 + m16, k = ch * 8 + j;
        Wf[o] = f2b(k < 51 ? We[k * 256 + n] : 0.f);
    } else if (b < 4648) {                        // bcat2 (2 blocks, 512)
        int idx = (b - 4646) * 256 + t;
        P.bcat2[idx] = idx < 256 ? P.bl2[idx] : P.br2[idx - 256];
    } else {                                      // composed W (64 blocks)
        int o = (b - 4648) * 256 + t;             // < 16384 = 512*32
        int n = o >> 5, k = o & 31;
        int nn = n & 255;
        const float* Wc = (n < 256) ? P.Wl1 : P.Wr1;
        float s = 0.f;
        if (k < 13)
            for (int m = 0; m < 128; m++)
                s = fmaf(P.W0[k * 128 + m], Wc[m * 256 + nn], s);
        P.Wct[n * 32 + k] = f2b(s);
        if (k == 0) {
            float bb = (n < 256) ? P.bl1[nn] : P.br1[nn];
            for (int m = 0; m < 128; m++)
                bb = fmaf(P.b0[m], Wc[m * 256 + nn], bb);
            P.bc[n] = bb;
        }
    }
}

// ===================== fused ee-MFMA + edge logit ========================
// R10 structure: 8KB ea tile staged into LDS via coalesced global_load_lds
// (reusing eeS's first 8KB), aF fragments read from LDS (bank conflicts
// hidden under xl gather latency). xl hoisted, xr late, split accumulator
// for 4 blocks/CU, staggered satt.
__global__ __launch_bounds__(256, 4) void edge_fused(
    const ushort* __restrict__ ea_frag, const ushort* __restrict__ Wfrag,
    const float* __restrict__ att,
    const int* __restrict__ src_csr, const int* __restrict__ dst_csr,
    const ushort* __restrict__ xlr, float* __restrict__ logitp) {
    __shared__ __align__(16) ushort eeS[64 * 256];   // 32 KB (first 8KB = ea stage)
    __shared__ float satt[4 * 72];                   // staggered, conflict-free
    const int tid = threadIdx.x, lane = tid & 63, wv = tid >> 6;
    const int tile = ((int)blockIdx.x & 7) * 586 + ((int)blockIdx.x >> 3);
    const int i0 = tile * 64;
    satt[(tid >> 6) * 72 + (tid & 63)] = att[tid];
    const int m16 = lane & 15, q = lane >> 4;

    // ---- hoisted: edge ids + xl[src] gathers (issued first, consumed late)
    const int el = tid >> 2, h = tid & 3;
    const int i = i0 + el;
    const bool live_e = (i < EE);
    const int ic = live_e ? i : (EE - 1);
    const int src = src_csr[ic], dstn = dst_csr[ic];
    const ushort* xlp = xlr + (size_t)src * 512 + h * 64;
    short8 xlv[8];
#pragma unroll
    for (int c = 0; c < 8; c++) xlv[c] = *(const short8*)(xlp + c * 8);

    // ---- stage the 8KB ea tile into LDS (coalesced, overlaps xl latency)
    const ushort* gtile = ea_frag + (size_t)i0 * 64;
    GLD16(gtile + tid * 8, &eeS[tid * 8]);
    GLD16(gtile + 2048 + tid * 8, &eeS[2048 + tid * 8]);
    __syncthreads();

    short8 zz;
#pragma unroll
    for (int z = 0; z < 8; z++) zz[z] = 0;

    // ea fragments from LDS (row-contiguous: row*64 + chunk*8 ushorts)
    short8 aF[2][4];
#pragma unroll
    for (int k0 = 0; k0 < 2; k0++)
#pragma unroll
        for (int r = 0; r < 4; r++)
            aF[k0][r] = (k0 == 1 && q == 3)
                ? zz
                : *(const short8*)&eeS[(r * 16 + m16) * 64 + (k0 * 4 + q) * 8];
    __syncthreads();   // all aF reads done before eeS is overwritten

#pragma unroll
    for (int h2 = 0; h2 < 2; h2++) {
        floatx4 acc[4][2];
#pragma unroll
        for (int r = 0; r < 4; r++)
#pragma unroll
            for (int c = 0; c < 2; c++) acc[r][c] = (floatx4){0.f, 0.f, 0.f, 0.f};
#pragma unroll
        for (int k0 = 0; k0 < 2; k0++) {
            const bool live = !(k0 == 1 && q == 3);
            short8 bF[2];
#pragma unroll
            for (int c = 0; c < 2; c++)
                bF[c] = live
                    ? *(const short8*)&Wfrag[(((wv * 4 + h2 * 2 + c) * 8 + k0 * 4 + q) * 16 + m16) * 8]
                    : zz;
#pragma unroll
            for (int r = 0; r < 4; r++)
#pragma unroll
                for (int c = 0; c < 2; c++)
                    acc[r][c] = __builtin_amdgcn_mfma_f32_16x16x32_bf16(
                        aF[k0][r], bF[c], acc[r][c], 0, 0, 0);
        }
#pragma unroll
        for (int r = 0; r < 4; r++)
#pragma unroll
            for (int cc = 0; cc < 2; cc++)
#pragma unroll
                for (int j = 0; j < 4; j++) {
                    int row = r * 16 + q * 4 + j;
                    int col = (wv * 4 + h2 * 2 + cc) * 16 + m16;
                    int chunk = col >> 3;
                    int P = EESWZ(chunk, row);
                    eeS[row * 256 + (P << 3) + (col & 7)] = f2b(acc[r][cc][j]);
                }
        // pin the half boundary: keeps the two acc lifetimes disjoint
        __builtin_amdgcn_sched_barrier(0);
    }
    __syncthreads();

    if (live_e) {
        const ushort* xrp = xlr + (size_t)dstn * 512 + 256 + h * 64;
        float s = 0.f;
#pragma unroll
        for (int c = 0; c < 8; c++) {
            short8 xrv = *(const short8*)(xrp + c * 8);
            int chunk = h * 8 + c;
            int P = EESWZ(chunk, el);
            short8 eev = *(const short8*)&eeS[el * 256 + (P << 3)];
#pragma unroll
            for (int j = 0; j < 8; j++) {
                float v = b2f(xlv[c][j]) + b2f(xrv[j]) + b2f(eev[j]);
                v = v > 0.f ? v : 0.2f * v;
                s += v * satt[h * 72 + c * 8 + j];
            }
        }
        logitp[(size_t)i * 4 + h] = s;
    }
}

// ===================== CSR build =========================================
__global__ void hist_deg(const int* __restrict__ ei, int* __restrict__ deg) {
    int e = blockIdx.x * 256 + threadIdx.x;
    if (e < EE) atomicAdd(&deg[ei[EE + e]], 1);
}
__global__ void scan1(const int* __restrict__ deg, int* __restrict__ partial,
                      int* __restrict__ bsum) {
    __shared__ int sh[256];
    int t = threadIdx.x, i = blockIdx.x * 256 + t;
    int v = (i < NN) ? deg[i] : 0;
    sh[t] = v; __syncthreads();
    for (int off = 1; off < 256; off <<= 1) {
        int x = (t >= off) ? sh[t - off] : 0;
        __syncthreads();
        sh[t] += x;
        __syncthreads();
    }
    if (i < NN) partial[i] = sh[t] - v;
    if (t == 255) bsum[blockIdx.x] = sh[255];
}
// R13: scan2 folded in — each block parallel-reduces its own bsum prefix
// (bsum has 118 entries, L2-hot; threads t<myb load, tree-sum).
__global__ void scan3(const int* __restrict__ partial, const int* __restrict__ bsum,
                      int* __restrict__ start, int* __restrict__ cursor) {
    __shared__ int sh[256];
    const int t = threadIdx.x;
    const int myb = blockIdx.x;
    int v = (t < myb && t < 118) ? bsum[t] : 0;
    sh[t] = v; __syncthreads();
    for (int off = 128; off; off >>= 1) {
        if (t < off) sh[t] += sh[t + off];
        __syncthreads();
    }
    const int pre = sh[0];
    int i = myb * 256 + t;
    if (i < NN) { start[i] = partial[i] + pre; cursor[i] = 0; }
    else if (i == NN) start[NN] = EE;
}
__global__ void scatter_e(const int* __restrict__ ei, int* __restrict__ cursor,
                          const int* __restrict__ start, int* __restrict__ einv,
                          int* __restrict__ src_csr, int* __restrict__ dst_csr) {
    int e = blockIdx.x * 256 + threadIdx.x;
    if (e >= EE) return;
    int s = ei[e];
    int d = ei[EE + e];
    int p = atomicAdd(&cursor[d], 1);
    int pos = start[d] + p;
    einv[e] = pos;            // inverse permutation (natural e -> CSR pos)
    src_csr[pos] = s;
    dst_csr[pos] = d;
}

// ===================== fused segment softmax + aggregate =================
// R11 XCD-aligned swizzle retained (mildly positive).
__global__ __launch_bounds__(256) void aggregate_csr(
    const ushort* __restrict__ xlr, const float* __restrict__ logitp,
    const int* __restrict__ src_csr, const int* __restrict__ start,
    const float* __restrict__ bias, ushort* __restrict__ outb) {
    const int lane = threadIdx.x & 63, wv = threadIdx.x >> 6;
    const int g = ((int)blockIdx.x & 7) * 938 + ((int)blockIdx.x >> 3);
    if (g >= (NN + 3) / 4) return;
    const int dst = g * 4 + wv;
    if (dst >= NN) return;
    const int s0 = start[dst];
    const int deg = start[dst + 1] - s0;
    const int h = lane >> 4;

    // ---- phase 1: per-head max + denom (lane-parallel over edges) ----
    float m[4] = {-3.4e38f, -3.4e38f, -3.4e38f, -3.4e38f};
    float lg[4] = {0.f, 0.f, 0.f, 0.f};
    bool lv = lane < deg;
    if (lv) {
        float4 l4 = ((const float4*)logitp)[s0 + lane];
        lg[0] = l4.x; lg[1] = l4.y; lg[2] = l4.z; lg[3] = l4.w;
        m[0] = l4.x; m[1] = l4.y; m[2] = l4.z; m[3] = l4.w;
    }
    for (int i = 64 + lane; i < deg; i += 64) {
        float4 l4 = ((const float4*)logitp)[s0 + i];
        m[0] = fmaxf(m[0], l4.x); m[1] = fmaxf(m[1], l4.y);
        m[2] = fmaxf(m[2], l4.z); m[3] = fmaxf(m[3], l4.w);
    }
#pragma unroll
    for (int off = 32; off; off >>= 1)
#pragma unroll
        for (int k = 0; k < 4; k++) m[k] = fmaxf(m[k], __shfl_xor(m[k], off));

    float d[4];
#pragma unroll
    for (int k = 0; k < 4; k++) d[k] = lv ? __expf(lg[k] - m[k]) : 0.f;
    for (int i = 64 + lane; i < deg; i += 64) {
        float4 l4 = ((const float4*)logitp)[s0 + i];
        d[0] += __expf(l4.x - m[0]); d[1] += __expf(l4.y - m[1]);
        d[2] += __expf(l4.z - m[2]); d[3] += __expf(l4.w - m[3]);
    }
#pragma unroll
    for (int off = 32; off; off >>= 1)
#pragma unroll
        for (int k = 0; k < 4; k++) d[k] += __shfl_xor(d[k], off);
    const float dh = 1.f / (((h == 0) ? d[0] : (h == 1) ? d[1] : (h == 2) ? d[2] : d[3]) + 1e-16f);
    const float mh = (h == 0) ? m[0] : (h == 1) ? m[1] : (h == 2) ? m[2] : m[3];

    // ---- phase 2: weighted gather (uniform loads, no shfl) ----
    float4 b4 = ((const float4*)bias)[lane];
    float a0 = b4.x, a1 = b4.y, a2 = b4.z, a3 = b4.w;

    const ushort* xbase = xlr + (size_t)lane * 4;
    const float* lgh = logitp + h;
    int i = 0;
    for (; i + 8 <= deg; i += 8) {
        int sv[8]; float aw[8];
#pragma unroll
        for (int u = 0; u < 8; u++) {
            sv[u] = src_csr[s0 + i + u];                     // uniform -> broadcast
            float lh = lgh[(size_t)(s0 + i + u) * 4];        // 1 line / wave
            aw[u] = __expf(lh - mh) * dh;
        }
        ushort4 xv[8];
#pragma unroll
        for (int u = 0; u < 8; u++)
            xv[u] = *(const ushort4*)(xbase + (size_t)sv[u] * 512);
#pragma unroll
        for (int u = 0; u < 8; u++) {
            a0 += b2f(xv[u].x) * aw[u]; a1 += b2f(xv[u].y) * aw[u];
            a2 += b2f(xv[u].z) * aw[u]; a3 += b2f(xv[u].w) * aw[u];
        }
    }
    for (; i < deg; i++) {
        int srcv = src_csr[s0 + i];
        float lh = lgh[(size_t)(s0 + i) * 4];
        float aw = __expf(lh - mh) * dh;
        ushort4 xv = *(const ushort4*)(xbase + (size_t)srcv * 512);
        a0 += b2f(xv.x) * aw; a1 += b2f(xv.y) * aw;
        a2 += b2f(xv.z) * aw; a3 += b2f(xv.w) * aw;
    }
    ushort4 ov;
    ov.x = f2b(a0); ov.y = f2b(a1); ov.z = f2b(a2); ov.w = f2b(a3);
    *(ushort4*)(outb + (size_t)dst * 256 + lane * 4) = ov;
}

// ===================== fused pooling (R13) ===============================
// One pass structure per graph: grid (BB,4), 64 threads; block handles 64
// channels of one graph. Node range via binary search on sorted batch.
// Replaces pool_max+pool_sums (and the am atomicMax machinery) with
// block-local max->sums; den/num written directly, no atomics.
__global__ void pool_fused(const __hip_bfloat16* __restrict__ a,
                           const __hip_bfloat16* __restrict__ h2,
                           const int* __restrict__ batch,
                           float* __restrict__ den, float* __restrict__ num) {
    const int b = blockIdx.x;
    const int c = blockIdx.y * 64 + threadIdx.x;
    __shared__ int s0s, s1s;
    if (threadIdx.x == 0) {
        int lo = 0, hi = NN;
        while (lo < hi) { int mid = (lo + hi) >> 1; if (batch[mid] < b) lo = mid + 1; else hi = mid; }
        s0s = lo;
    }
    if (threadIdx.x == 1) {
        int lo = 0, hi = NN;
        while (lo < hi) { int mid = (lo + hi) >> 1; if (batch[mid] < b + 1) lo = mid + 1; else hi = mid; }
        s1s = lo;
    }
    __syncthreads();
    const int n0 = s0s, n1 = s1s;
    float m = -3.4e38f;
    for (int n = n0; n < n1; n++)
        m = fmaxf(m, __bfloat162float(a[(size_t)n * HC + c]));
    float sd = 0.f, sn = 0.f;
    for (int n = n0; n < n1; n++) {
        float w = __expf(__bfloat162float(a[(size_t)n * HC + c]) - m);
        sd += w;
        sn += __bfloat162float(h2[(size_t)n * HC + c]) * w;
    }
    den[b * HC + c] = sd;
    num[b * HC + c] = sn;
}

// ===================== head MLP ==========================================
__global__ void mlp_lin1(const float* __restrict__ num, const float* __restrict__ den,
                         const float* __restrict__ Wo1, const float* __restrict__ bo1,
                         float* __restrict__ y) {
    __shared__ float gsh[HC];
    const int c = threadIdx.x;
    const int r = blockIdx.x;
    gsh[c] = num[r * HC + c] / (den[r * HC + c] + 1e-16f);
    __syncthreads();
    float acc = bo1[c];
#pragma unroll 4
    for (int k = 0; k < HC; k++) acc = fmaf(gsh[k], Wo1[k * HC + c], acc);
    y[r * HC + c] = acc;
}
// bn_relu folded into lin2 (R12): per-block column stats from raw y.
__global__ void bn_lin2(const float* __restrict__ y, const float* __restrict__ gamma,
                        const float* __restrict__ beta, const float* __restrict__ Wo2,
                        const float* __restrict__ bo2, float* __restrict__ out) {
    __shared__ float ysh[HC];
    const int t = threadIdx.x;
    const int r = blockIdx.y;
    float s = 0.f, sq = 0.f;
    for (int rr = 0; rr < BB; rr++) { float v = y[rr * HC + t]; s += v; sq += v * v; }
    float mu  = s * (1.f / BB);
    float var = sq * (1.f / BB) - mu * mu;
    float inv = rsqrtf(var + 1e-5f) * gamma[t];
    float v = (y[r * HC + t] - mu) * inv + beta[t];
    ysh[t] = v > 0.f ? v : 0.f;
    __syncthreads();
    int j = blockIdx.x * 256 + t;
    if (j >= 2001) return;
    float acc = bo2[j];
#pragma unroll 4
    for (int k = 0; k < HC; k++) acc = fmaf(ysh[k], Wo2[k * 2001 + j], acc);
    out[r * 2001 + j] = acc > 0.f ? acc : 0.01f * acc;
}

// ===================== launcher ==========================================
extern "C" void kernel_launch(void* const* d_in, const int* in_sizes, int n_in,
                              void* d_out, int out_size, void* d_ws, size_t ws_size,
                              hipStream_t stream) {
    const float* x     = (const float*)d_in[0];
    const int*   ei    = (const int*)d_in[1];
    const float* ea    = (const float*)d_in[2];
    const int*   batch = (const int*)d_in[3];
    const float* W0 = (const float*)d_in[4];  const float* b0 = (const float*)d_in[5];
    const float* Wl1 = (const float*)d_in[6]; const float* bl1 = (const float*)d_in[7];
    const float* Wr1 = (const float*)d_in[8]; const float* br1 = (const float*)d_in[9];
    const float* We1 = (const float*)d_in[10]; const float* att1 = (const float*)d_in[11];
    const float* bias1 = (const float*)d_in[12];
    const float* Wl2 = (const float*)d_in[13]; const float* bl2 = (const float*)d_in[14];
    const float* Wr2 = (const float*)d_in[15]; const float* br2 = (const float*)d_in[16];
    const float* We2 = (const float*)d_in[17]; const float* att2 = (const float*)d_in[18];
    const float* bias2 = (const float*)d_in[19];
    const float* Wp = (const float*)d_in[20]; const float* bp = (const float*)d_in[21];
    const float* Wo1 = (const float*)d_in[22]; const float* bo1 = (const float*)d_in[23];
    const float* gamma = (const float*)d_in[24]; const float* beta = (const float*)d_in[25];
    const float* Wo2 = (const float*)d_in[26]; const float* bo2 = (const float*)d_in[27];
    float* out = (float*)d_out;

    char* p = (char*)d_ws;
    auto alloc = [&](size_t bytes) { char* r = p; p += (bytes + 255) & ~(size_t)255; return r; };
    const int MP = 30016;
    const int ET = 4688;
    __hip_bfloat16* xpad  = (__hip_bfloat16*)alloc((size_t)MP * 32 * 2);
    __hip_bfloat16* W2t   = (__hip_bfloat16*)alloc(512 * 256 * 2);
    __hip_bfloat16* Wpt   = (__hip_bfloat16*)alloc(256 * 256 * 2);
    ushort* Wef1 = (ushort*)alloc(256 * 64 * 2);
    ushort* Wef2 = (ushort*)alloc(256 * 64 * 2);
    ushort* Wct  = (ushort*)alloc(512 * 32 * 2);
    float* bc    = (float*)alloc(512 * 4);
    float* bcat2 = (float*)alloc(512 * 4);
    __hip_bfloat16* xlrb = (__hip_bfloat16*)alloc((size_t)MP * 512 * 2);
    __hip_bfloat16* h1b  = (__hip_bfloat16*)alloc((size_t)MP * 256 * 2);
    __hip_bfloat16* h2b  = (__hip_bfloat16*)alloc((size_t)MP * 256 * 2);
    ushort* ea_frag = (ushort*)alloc((size_t)ET * 4096 * 2);
    __hip_bfloat16* abuf = (__hip_bfloat16*)alloc((size_t)MP * 256 * 2);
    float* logit = (float*)alloc((size_t)EE * 4 * 4);
    int* deg    = (int*)alloc(NN * 4);
    int* cursor = (int*)alloc(NN * 4);
    int* partial= (int*)alloc(NN * 4);
    int* bsum   = (int*)alloc(256 * 4);
    int* start  = (int*)alloc((NN + 4) * 4);
    int* einv   = (int*)alloc((size_t)EE * 4);
    int* src_csr= (int*)alloc((size_t)EE * 4);
    int* dst_csr= (int*)alloc((size_t)EE * 4);
    float* den  = (float*)alloc(BB * HC * 4);
    float* num  = (float*)alloc(BB * HC * 4);
    float* ybuf = (float*)alloc(BB * HC * 4);

    const int NB = (NN + 255) / 256;

    // ---- consolidated setup (packing + weight transforms + composition) ----
    SetupParams sp;
    sp.x = x; sp.W0 = W0; sp.b0 = b0; sp.Wl1 = Wl1; sp.Wr1 = Wr1;
    sp.Wl2 = Wl2; sp.Wr2 = Wr2; sp.Wp = Wp; sp.We1 = We1; sp.We2 = We2;
    sp.bl1 = bl1; sp.br1 = br1; sp.bl2 = bl2; sp.br2 = br2;
    sp.xpad = xpad; sp.W2t = W2t; sp.Wpt = Wpt;
    sp.Wef1 = Wef1; sp.Wef2 = Wef2; sp.Wct = Wct;
    sp.bcat2 = bcat2; sp.bc = bc; sp.deg = deg;
    setup_all<<<4712, 256, 0, stream>>>(sp);

    // ---- CSR build ----
    hist_deg<<<(EE + 255) / 256, 256, 0, stream>>>(ei, deg);
    scan1<<<NB, 256, 0, stream>>>(deg, partial, bsum);
    scan3<<<NB + 1, 256, 0, stream>>>(partial, bsum, start, cursor);
    scatter_e<<<(EE + 255) / 256, 256, 0, stream>>>(ei, cursor, start, einv, src_csr, dst_csr);
    // coalesced-read / full-line scattered-write permute
    permute_ea_frag<<<9376, 256, 0, stream>>>(ea, einv, ea_frag);

    // ---- GAT layer 1 (init transform composed into weights: K=32) ----
    mfma_gemm<4><<<dim3(469, 2), 256, 0, stream>>>(
        (const ushort*)xpad, Wct, bc, nullptr, xlrb, NN, 512, 32);
    edge_fused<<<ET, 256, 0, stream>>>(ea_frag, Wef1, att1, src_csr, dst_csr,
                                       (const ushort*)xlrb, logit);
    aggregate_csr<<<7504, 256, 0, stream>>>(
        (const ushort*)xlrb, logit, src_csr, start, bias1, (ushort*)h1b);

    // ---- GAT layer 2 ----
    mfma_gemm<4><<<dim3(469, 2), 256, 0, stream>>>(
        (const ushort*)h1b, (const ushort*)W2t, bcat2, nullptr, xlrb, NN, 512, 256);
    edge_fused<<<ET, 256, 0, stream>>>(ea_frag, Wef2, att2, src_csr, dst_csr,
                                       (const ushort*)xlrb, logit);
    aggregate_csr<<<7504, 256, 0, stream>>>(
        (const ushort*)xlrb, logit, src_csr, start, bias2, (ushort*)h2b);

    // ---- attention pooling ----
    mfma_gemm<4><<<dim3(469, 1), 256, 0, stream>>>(
        (const ushort*)h2b, (const ushort*)Wpt, bp, nullptr, abuf, NN, 256, 256);
    pool_fused<<<dim3(BB, 4), 64, 0, stream>>>(abuf, h2b, batch, den, num);

    // ---- head MLP ----
    mlp_lin1<<<BB, HC, 0, stream>>>(num, den, Wo1, bo1, ybuf);
    bn_lin2<<<dim3(8, BB), 256, 0, stream>>>(ybuf, gamma, beta, Wo2, bo2, out);
}

// Round 14
// 536.347 us; speedup vs baseline: 1.3025x; 1.3025x over previous
//
#include <hip/hip_runtime.h>
#include <hip/hip_bf16.h>

#define NN 30000
#define EE 300000
#define BB 64
#define HH 4
#define CC 64
#define HC 256

typedef __attribute__((ext_vector_type(8))) short short8;
typedef __attribute__((ext_vector_type(4))) float floatx4;

__device__ __forceinline__ float b2f(short x) {
    return __uint_as_float(((unsigned)(unsigned short)x) << 16);
}
__device__ __forceinline__ unsigned short f2b(float f) {
    __hip_bfloat16 h = __float2bfloat16(f);
    return *(unsigned short*)&h;
}

#define GLD16(gp, lp) __builtin_amdgcn_global_load_lds( \
    (const __attribute__((address_space(1))) void*)(gp), \
    (__attribute__((address_space(3))) void*)(lp), 16, 0, 0)

#define ROT2(x) ((((x) << 2) | ((x) >> 3)) & 31)
#define EESWZ(chunk, row) (ROT2(chunk) ^ (((row) >> 2) & 3) ^ (((row) & 1) << 2))

// ===================== bf16 MFMA GEMM (dense transforms) =================
template<int CT>
__global__ __launch_bounds__(256) void mfma_gemm(
    const ushort* __restrict__ A, const ushort* __restrict__ Bt,
    const float* __restrict__ bias, float* __restrict__ outF,
    __hip_bfloat16* __restrict__ outB, int M, int Nc, int K) {
    constexpr int SMEM_USHORTS =
        ((64 * 32 + CT * 64 * 32) > (64 * CT * 64)) ? (64 * 32 + CT * 64 * 32)
                                                    : (64 * CT * 64);
    __shared__ __align__(16) ushort smem[SMEM_USHORTS];
    ushort* lA = smem;
    ushort* lB = smem + 64 * 32;
    const int tid = threadIdx.x, lane = tid & 63, wv = tid >> 6;
    const int row0 = blockIdx.x * 64, col0 = blockIdx.y * (CT * 64);

    floatx4 acc[4][CT];
#pragma unroll
    for (int r = 0; r < 4; r++)
#pragma unroll
        for (int c = 0; c < CT; c++) acc[r][c] = (floatx4){0.f, 0.f, 0.f, 0.f};

    const int arow = tid >> 2;
    const int sl   = (tid & 3) ^ ((tid >> 3) & 3);
    const ushort* ga = A + (size_t)(row0 + arow) * K + sl * 8;
    const int m16 = lane & 15, q = lane >> 4;

    for (int k0 = 0; k0 < K; k0 += 32) {
        __syncthreads();
        GLD16(ga + k0, &lA[tid * 8]);
#pragma unroll
        for (int j = 0; j < CT; j++) {
            const ushort* gb = Bt + (size_t)(col0 + j * 64 + arow) * K + k0 + sl * 8;
            GLD16(gb, &lB[j * 2048 + tid * 8]);
        }
        __syncthreads();
        short8 aF[4], bF[CT];
#pragma unroll
        for (int r = 0; r < 4; r++) {
            int rr = r * 16 + m16;
            aF[r] = *(const short8*)&lA[rr * 32 + ((q ^ ((rr >> 1) & 3)) << 3)];
        }
#pragma unroll
        for (int c = 0; c < CT; c++) {
            int nr = (wv * CT + c) * 16 + m16;
            bF[c] = *(const short8*)&lB[nr * 32 + ((q ^ ((nr >> 1) & 3)) << 3)];
        }
#pragma unroll
        for (int r = 0; r < 4; r++)
#pragma unroll
            for (int c = 0; c < CT; c++)
                acc[r][c] = __builtin_amdgcn_mfma_f32_16x16x32_bf16(aF[r], bF[c], acc[r][c], 0, 0, 0);
    }

    if (outB != nullptr) {
        __syncthreads();
#pragma unroll
        for (int c = 0; c < CT; c++) {
            int lcol = (wv * CT + c) * 16 + m16;
            float bv = bias ? bias[col0 + lcol] : 0.f;
            int ch = lcol >> 3, c7 = lcol & 7;
#pragma unroll
            for (int r = 0; r < 4; r++)
#pragma unroll
                for (int j = 0; j < 4; j++) {
                    int row = r * 16 + q * 4 + j;
                    smem[row * (CT * 64) + ((ch ^ (row & 7)) << 3) + c7] =
                        f2b(acc[r][c][j] + bv);
                }
        }
        __syncthreads();
        constexpr int SH = (CT == 4) ? 5 : 4;
#pragma unroll
        for (int s = 0; s < CT * 2; s++) {
            int g = tid + 256 * s;
            int row = g >> SH, ch = g & (CT * 8 - 1);
            int grow = row0 + row;
            if (grow < M) {
                short8 v = *(const short8*)&smem[row * (CT * 64) + ((ch ^ (row & 7)) << 3)];
                *(short8*)((ushort*)outB + (size_t)grow * Nc + col0 + ch * 8) = v;
            }
        }
    } else {
#pragma unroll
        for (int c = 0; c < CT; c++) {
            int col = col0 + (wv * CT + c) * 16 + m16;
            float bv = bias ? bias[col] : 0.f;
#pragma unroll
            for (int r = 0; r < 4; r++)
#pragma unroll
                for (int j = 0; j < 4; j++) {
                    int row = row0 + r * 16 + q * 4 + j;
                    if (row < M) outF[(size_t)row * Nc + col] = acc[r][c][j] + bv;
                }
        }
    }
}

// ===================== ea -> row-contiguous bf16 (CSR order) =============
__global__ void permute_ea_frag(const float* __restrict__ ea,
                                const int* __restrict__ einv,
                                ushort* __restrict__ ea_frag) {
    const int t = blockIdx.x * 256 + threadIdx.x;
    const int e = t >> 3, ch = t & 7;
    if (e >= 300032) return;
    const bool live = e < EE;
    const int p = live ? einv[e] : e;
    short8 v8;
#pragma unroll
    for (int j = 0; j < 8; j++) {
        int k = ch * 8 + j;
        float v = (live && k < 51) ? ea[(size_t)e * 51 + k] : 0.f;
        v8[j] = (short)f2b(v);
    }
    *(short8*)&ea_frag[(size_t)p * 64 + ch * 8] = v8;
}

// ===================== consolidated setup (R13) ==========================
// pack_x + W2t/Wpt packs + we_frag + bcat2 + COMPOSED layer-1 weights:
// Wc = W0@[Wl1|Wr1] (13x512, K padded to 32, B^T layout), bc = b0@[..]+[bl|br].
// Removes the init GEMM dispatch and cuts layer-1 K 128->32.
struct SetupParams {
    const float *x, *W0, *b0, *Wl1, *Wr1, *Wl2, *Wr2, *Wp, *We1, *We2;
    const float *bl1, *br1, *bl2, *br2;
    __hip_bfloat16 *xpad, *W2t, *Wpt;
    ushort *Wef1, *Wef2, *Wct;
    float *bcat2, *bc;
    int *deg;
    unsigned *am;
};
__global__ void setup_all(SetupParams P) {
    const int b = blockIdx.x, t = threadIdx.x;
    if (b < 3750) {                               // pack_x + deg zero + am zero
        int i = b * 256 + t;
        if (i < NN) P.deg[i] = 0;
        if (i < BB * HC) P.am[i] = 0u;
        int n = i >> 5, k = i & 31;
        P.xpad[i] = __float2bfloat16(k < 13 ? P.x[n * 13 + k] : 0.f);
    } else if (b < 4006) {                        // W2t left (Wl2, K=256)
        int o = (b - 3750) * 256 + t;             // < 65536
        int n = o >> 8, k = o & 255;
        P.W2t[(size_t)n * 256 + k] = __float2bfloat16(P.Wl2[k * 256 + n]);
    } else if (b < 4262) {                        // W2t right (Wr2, rowoff 256)
        int o = (b - 4006) * 256 + t;
        int n = o >> 8, k = o & 255;
        P.W2t[(size_t)(256 + n) * 256 + k] = __float2bfloat16(P.Wr2[k * 256 + n]);
    } else if (b < 4518) {                        // Wpt (Wp, K=256)
        int o = (b - 4262) * 256 + t;
        int n = o >> 8, k = o & 255;
        P.Wpt[(size_t)n * 256 + k] = __float2bfloat16(P.Wp[k * 256 + n]);
    } else if (b < 4646) {                        // we_frag (We1 then We2)
        int which = (b - 4518) >> 6;
        int o = ((b - 4518) & 63) * 256 + t;      // < 16384
        const float* We = which ? P.We2 : P.We1;
        ushort* Wf = which ? P.Wef2 : P.Wef1;
        int j = o & 7, m16 = (o >> 3) & 15, ch = (o >> 7) & 7, nt = o >> 10;
        int n = nt * 16 + m16, k = ch * 8 + j;
        Wf[o] = f2b(k < 51 ? We[k * 256 + n] : 0.f);
    } else if (b < 4648) {                        // bcat2 (2 blocks, 512)
        int idx = (b - 4646) * 256 + t;
        P.bcat2[idx] = idx < 256 ? P.bl2[idx] : P.br2[idx - 256];
    } else {                                      // composed W (64 blocks)
        int o = (b - 4648) * 256 + t;             // < 16384 = 512*32
        int n = o >> 5, k = o & 31;
        int nn = n & 255;
        const float* Wc = (n < 256) ? P.Wl1 : P.Wr1;
        float s = 0.f;
        if (k < 13)
            for (int m = 0; m < 128; m++)
                s = fmaf(P.W0[k * 128 + m], Wc[m * 256 + nn], s);
        P.Wct[n * 32 + k] = f2b(s);
        if (k == 0) {
            float bb = (n < 256) ? P.bl1[nn] : P.br1[nn];
            for (int m = 0; m < 128; m++)
                bb = fmaf(P.b0[m], Wc[m * 256 + nn], bb);
            P.bc[n] = bb;
        }
    }
}

// ===================== fused ee-MFMA + edge logit ========================
// R10 structure: 8KB ea tile staged into LDS via coalesced global_load_lds
// (reusing eeS's first 8KB), aF fragments read from LDS (bank conflicts
// hidden under xl gather latency). xl hoisted, xr late, split accumulator
// for 4 blocks/CU, staggered satt.
__global__ __launch_bounds__(256, 4) void edge_fused(
    const ushort* __restrict__ ea_frag, const ushort* __restrict__ Wfrag,
    const float* __restrict__ att,
    const int* __restrict__ src_csr, const int* __restrict__ dst_csr,
    const ushort* __restrict__ xlr, float* __restrict__ logitp) {
    __shared__ __align__(16) ushort eeS[64 * 256];   // 32 KB (first 8KB = ea stage)
    __shared__ float satt[4 * 72];                   // staggered, conflict-free
    const int tid = threadIdx.x, lane = tid & 63, wv = tid >> 6;
    const int tile = ((int)blockIdx.x & 7) * 586 + ((int)blockIdx.x >> 3);
    const int i0 = tile * 64;
    satt[(tid >> 6) * 72 + (tid & 63)] = att[tid];
    const int m16 = lane & 15, q = lane >> 4;

    // ---- hoisted: edge ids + xl[src] gathers (issued first, consumed late)
    const int el = tid >> 2, h = tid & 3;
    const int i = i0 + el;
    const bool live_e = (i < EE);
    const int ic = live_e ? i : (EE - 1);
    const int src = src_csr[ic], dstn = dst_csr[ic];
    const ushort* xlp = xlr + (size_t)src * 512 + h * 64;
    short8 xlv[8];
#pragma unroll
    for (int c = 0; c < 8; c++) xlv[c] = *(const short8*)(xlp + c * 8);

    // ---- stage the 8KB ea tile into LDS (coalesced, overlaps xl latency)
    const ushort* gtile = ea_frag + (size_t)i0 * 64;
    GLD16(gtile + tid * 8, &eeS[tid * 8]);
    GLD16(gtile + 2048 + tid * 8, &eeS[2048 + tid * 8]);
    __syncthreads();

    short8 zz;
#pragma unroll
    for (int z = 0; z < 8; z++) zz[z] = 0;

    // ea fragments from LDS (row-contiguous: row*64 + chunk*8 ushorts)
    short8 aF[2][4];
#pragma unroll
    for (int k0 = 0; k0 < 2; k0++)
#pragma unroll
        for (int r = 0; r < 4; r++)
            aF[k0][r] = (k0 == 1 && q == 3)
                ? zz
                : *(const short8*)&eeS[(r * 16 + m16) * 64 + (k0 * 4 + q) * 8];
    __syncthreads();   // all aF reads done before eeS is overwritten

#pragma unroll
    for (int h2 = 0; h2 < 2; h2++) {
        floatx4 acc[4][2];
#pragma unroll
        for (int r = 0; r < 4; r++)
#pragma unroll
            for (int c = 0; c < 2; c++) acc[r][c] = (floatx4){0.f, 0.f, 0.f, 0.f};
#pragma unroll
        for (int k0 = 0; k0 < 2; k0++) {
            const bool live = !(k0 == 1 && q == 3);
            short8 bF[2];
#pragma unroll
            for (int c = 0; c < 2; c++)
                bF[c] = live
                    ? *(const short8*)&Wfrag[(((wv * 4 + h2 * 2 + c) * 8 + k0 * 4 + q) * 16 + m16) * 8]
                    : zz;
#pragma unroll
            for (int r = 0; r < 4; r++)
#pragma unroll
                for (int c = 0; c < 2; c++)
                    acc[r][c] = __builtin_amdgcn_mfma_f32_16x16x32_bf16(
                        aF[k0][r], bF[c], acc[r][c], 0, 0, 0);
        }
#pragma unroll
        for (int r = 0; r < 4; r++)
#pragma unroll
            for (int cc = 0; cc < 2; cc++)
#pragma unroll
                for (int j = 0; j < 4; j++) {
                    int row = r * 16 + q * 4 + j;
                    int col = (wv * 4 + h2 * 2 + cc) * 16 + m16;
                    int chunk = col >> 3;
                    int P = EESWZ(chunk, row);
                    eeS[row * 256 + (P << 3) + (col & 7)] = f2b(acc[r][cc][j]);
                }
        // pin the half boundary: keeps the two acc lifetimes disjoint
        __builtin_amdgcn_sched_barrier(0);
    }
    __syncthreads();

    if (live_e) {
        const ushort* xrp = xlr + (size_t)dstn * 512 + 256 + h * 64;
        float s = 0.f;
#pragma unroll
        for (int c = 0; c < 8; c++) {
            short8 xrv = *(const short8*)(xrp + c * 8);
            int chunk = h * 8 + c;
            int P = EESWZ(chunk, el);
            short8 eev = *(const short8*)&eeS[el * 256 + (P << 3)];
#pragma unroll
            for (int j = 0; j < 8; j++) {
                float v = b2f(xlv[c][j]) + b2f(xrv[j]) + b2f(eev[j]);
                v = v > 0.f ? v : 0.2f * v;
                s += v * satt[h * 72 + c * 8 + j];
            }
        }
        logitp[(size_t)i * 4 + h] = s;
    }
}

// ===================== CSR build =========================================
__global__ void hist_deg(const int* __restrict__ ei, int* __restrict__ deg) {
    int e = blockIdx.x * 256 + threadIdx.x;
    if (e < EE) atomicAdd(&deg[ei[EE + e]], 1);
}
__global__ void scan1(const int* __restrict__ deg, int* __restrict__ partial,
                      int* __restrict__ bsum) {
    __shared__ int sh[256];
    int t = threadIdx.x, i = blockIdx.x * 256 + t;
    int v = (i < NN) ? deg[i] : 0;
    sh[t] = v; __syncthreads();
    for (int off = 1; off < 256; off <<= 1) {
        int x = (t >= off) ? sh[t - off] : 0;
        __syncthreads();
        sh[t] += x;
        __syncthreads();
    }
    if (i < NN) partial[i] = sh[t] - v;
    if (t == 255) bsum[blockIdx.x] = sh[255];
}
// scan2 folded in (R13): each block parallel-reduces its own bsum prefix.
__global__ void scan3(const int* __restrict__ partial, const int* __restrict__ bsum,
                      int* __restrict__ start, int* __restrict__ cursor) {
    __shared__ int sh[256];
    const int t = threadIdx.x;
    const int myb = blockIdx.x;
    int v = (t < myb && t < 118) ? bsum[t] : 0;
    sh[t] = v; __syncthreads();
    for (int off = 128; off; off >>= 1) {
        if (t < off) sh[t] += sh[t + off];
        __syncthreads();
    }
    const int pre = sh[0];
    int i = myb * 256 + t;
    if (i < NN) { start[i] = partial[i] + pre; cursor[i] = 0; }
    else if (i == NN) start[NN] = EE;
}
__global__ void scatter_e(const int* __restrict__ ei, int* __restrict__ cursor,
                          const int* __restrict__ start, int* __restrict__ einv,
                          int* __restrict__ src_csr, int* __restrict__ dst_csr) {
    int e = blockIdx.x * 256 + threadIdx.x;
    if (e >= EE) return;
    int s = ei[e];
    int d = ei[EE + e];
    int p = atomicAdd(&cursor[d], 1);
    int pos = start[d] + p;
    einv[e] = pos;            // inverse permutation (natural e -> CSR pos)
    src_csr[pos] = s;
    dst_csr[pos] = d;
}

// ===================== fused segment softmax + aggregate =================
// R11 XCD-aligned swizzle retained (mildly positive).
__global__ __launch_bounds__(256) void aggregate_csr(
    const ushort* __restrict__ xlr, const float* __restrict__ logitp,
    const int* __restrict__ src_csr, const int* __restrict__ start,
    const float* __restrict__ bias, ushort* __restrict__ outb) {
    const int lane = threadIdx.x & 63, wv = threadIdx.x >> 6;
    const int g = ((int)blockIdx.x & 7) * 938 + ((int)blockIdx.x >> 3);
    if (g >= (NN + 3) / 4) return;
    const int dst = g * 4 + wv;
    if (dst >= NN) return;
    const int s0 = start[dst];
    const int deg = start[dst + 1] - s0;
    const int h = lane >> 4;

    // ---- phase 1: per-head max + denom (lane-parallel over edges) ----
    float m[4] = {-3.4e38f, -3.4e38f, -3.4e38f, -3.4e38f};
    float lg[4] = {0.f, 0.f, 0.f, 0.f};
    bool lv = lane < deg;
    if (lv) {
        float4 l4 = ((const float4*)logitp)[s0 + lane];
        lg[0] = l4.x; lg[1] = l4.y; lg[2] = l4.z; lg[3] = l4.w;
        m[0] = l4.x; m[1] = l4.y; m[2] = l4.z; m[3] = l4.w;
    }
    for (int i = 64 + lane; i < deg; i += 64) {
        float4 l4 = ((const float4*)logitp)[s0 + i];
        m[0] = fmaxf(m[0], l4.x); m[1] = fmaxf(m[1], l4.y);
        m[2] = fmaxf(m[2], l4.z); m[3] = fmaxf(m[3], l4.w);
    }
#pragma unroll
    for (int off = 32; off; off >>= 1)
#pragma unroll
        for (int k = 0; k < 4; k++) m[k] = fmaxf(m[k], __shfl_xor(m[k], off));

    float d[4];
#pragma unroll
    for (int k = 0; k < 4; k++) d[k] = lv ? __expf(lg[k] - m[k]) : 0.f;
    for (int i = 64 + lane; i < deg; i += 64) {
        float4 l4 = ((const float4*)logitp)[s0 + i];
        d[0] += __expf(l4.x - m[0]); d[1] += __expf(l4.y - m[1]);
        d[2] += __expf(l4.z - m[2]); d[3] += __expf(l4.w - m[3]);
    }
#pragma unroll
    for (int off = 32; off; off >>= 1)
#pragma unroll
        for (int k = 0; k < 4; k++) d[k] += __shfl_xor(d[k], off);
    const float dh = 1.f / (((h == 0) ? d[0] : (h == 1) ? d[1] : (h == 2) ? d[2] : d[3]) + 1e-16f);
    const float mh = (h == 0) ? m[0] : (h == 1) ? m[1] : (h == 2) ? m[2] : m[3];

    // ---- phase 2: weighted gather (uniform loads, no shfl) ----
    float4 b4 = ((const float4*)bias)[lane];
    float a0 = b4.x, a1 = b4.y, a2 = b4.z, a3 = b4.w;

    const ushort* xbase = xlr + (size_t)lane * 4;
    const float* lgh = logitp + h;
    int i = 0;
    for (; i + 8 <= deg; i += 8) {
        int sv[8]; float aw[8];
#pragma unroll
        for (int u = 0; u < 8; u++) {
            sv[u] = src_csr[s0 + i + u];                     // uniform -> broadcast
            float lh = lgh[(size_t)(s0 + i + u) * 4];        // 1 line / wave
            aw[u] = __expf(lh - mh) * dh;
        }
        ushort4 xv[8];
#pragma unroll
        for (int u = 0; u < 8; u++)
            xv[u] = *(const ushort4*)(xbase + (size_t)sv[u] * 512);
#pragma unroll
        for (int u = 0; u < 8; u++) {
            a0 += b2f(xv[u].x) * aw[u]; a1 += b2f(xv[u].y) * aw[u];
            a2 += b2f(xv[u].z) * aw[u]; a3 += b2f(xv[u].w) * aw[u];
        }
    }
    for (; i < deg; i++) {
        int srcv = src_csr[s0 + i];
        float lh = lgh[(size_t)(s0 + i) * 4];
        float aw = __expf(lh - mh) * dh;
        ushort4 xv = *(const ushort4*)(xbase + (size_t)srcv * 512);
        a0 += b2f(xv.x) * aw; a1 += b2f(xv.y) * aw;
        a2 += b2f(xv.z) * aw; a3 += b2f(xv.w) * aw;
    }
    ushort4 ov;
    ov.x = f2b(a0); ov.y = f2b(a1); ov.z = f2b(a2); ov.w = f2b(a3);
    *(ushort4*)(outb + (size_t)dst * 256 + lane * 4) = ov;
}

// ===================== pooling: chunk-parallel (R12-proven, reverted) ====
// R13's pool_fused was 202us at 2.7% occupancy (256 waves total on 256 CUs
// -> 1 wave/CU, no latency hiding). Reverted to the 469-block x 256-thread
// two-pass scheme with atomic stitching across chunk boundaries (~25us).
__device__ __forceinline__ unsigned fmap(float f) {
    unsigned u = __float_as_uint(f);
    return (u & 0x80000000u) ? ~u : (u | 0x80000000u);
}
__device__ __forceinline__ float funmap(unsigned u) {
    return (u & 0x80000000u) ? __uint_as_float(u & 0x7FFFFFFFu)
                             : __uint_as_float(~u);
}

__global__ void pool_max(const __hip_bfloat16* __restrict__ a, const int* __restrict__ batch,
                         unsigned* __restrict__ am, float* __restrict__ den,
                         float* __restrict__ num) {
    const int c = threadIdx.x;
    if (blockIdx.x < BB) {
        den[blockIdx.x * HC + c] = 0.f;
        num[blockIdx.x * HC + c] = 0.f;
    }
    const int n0 = blockIdx.x * 64;
    int curb = batch[n0];
    float m = -3.4e38f;
    const int nend = min(n0 + 64, NN);
    for (int n = n0; n < nend; n++) {
        int b = batch[n];
        float v = __bfloat162float(a[(size_t)n * HC + c]);
        if (b != curb) { atomicMax(&am[curb * HC + c], fmap(m)); curb = b; m = v; }
        else           { m = fmaxf(m, v); }
    }
    atomicMax(&am[curb * HC + c], fmap(m));
}
__global__ void pool_sums(const __hip_bfloat16* __restrict__ a,
                          const __hip_bfloat16* __restrict__ h2,
                          const int* __restrict__ batch, const unsigned* __restrict__ am,
                          float* __restrict__ den, float* __restrict__ num) {
    const int c = threadIdx.x;
    const int n0 = blockIdx.x * 64;
    int curb = batch[n0];
    float sd = 0.f, sn = 0.f;
    float mcur = funmap(am[curb * HC + c]);
    const int nend = min(n0 + 64, NN);
    for (int n = n0; n < nend; n++) {
        int b = batch[n];
        if (b != curb) {
            atomicAdd(&den[curb * HC + c], sd);
            atomicAdd(&num[curb * HC + c], sn);
            curb = b; sd = 0.f; sn = 0.f; mcur = funmap(am[b * HC + c]);
        }
        float w = __expf(__bfloat162float(a[(size_t)n * HC + c]) - mcur);
        sd += w;
        sn += __bfloat162float(h2[(size_t)n * HC + c]) * w;
    }
    atomicAdd(&den[curb * HC + c], sd);
    atomicAdd(&num[curb * HC + c], sn);
}

// ===================== head MLP ==========================================
__global__ void mlp_lin1(const float* __restrict__ num, const float* __restrict__ den,
                         const float* __restrict__ Wo1, const float* __restrict__ bo1,
                         float* __restrict__ y) {
    __shared__ float gsh[HC];
    const int c = threadIdx.x;
    const int r = blockIdx.x;
    gsh[c] = num[r * HC + c] / (den[r * HC + c] + 1e-16f);
    __syncthreads();
    float acc = bo1[c];
#pragma unroll 4
    for (int k = 0; k < HC; k++) acc = fmaf(gsh[k], Wo1[k * HC + c], acc);
    y[r * HC + c] = acc;
}
// bn_relu folded into lin2 (R12): per-block column stats from raw y.
__global__ void bn_lin2(const float* __restrict__ y, const float* __restrict__ gamma,
                        const float* __restrict__ beta, const float* __restrict__ Wo2,
                        const float* __restrict__ bo2, float* __restrict__ out) {
    __shared__ float ysh[HC];
    const int t = threadIdx.x;
    const int r = blockIdx.y;
    float s = 0.f, sq = 0.f;
    for (int rr = 0; rr < BB; rr++) { float v = y[rr * HC + t]; s += v; sq += v * v; }
    float mu  = s * (1.f / BB);
    float var = sq * (1.f / BB) - mu * mu;
    float inv = rsqrtf(var + 1e-5f) * gamma[t];
    float v = (y[r * HC + t] - mu) * inv + beta[t];
    ysh[t] = v > 0.f ? v : 0.f;
    __syncthreads();
    int j = blockIdx.x * 256 + t;
    if (j >= 2001) return;
    float acc = bo2[j];
#pragma unroll 4
    for (int k = 0; k < HC; k++) acc = fmaf(ysh[k], Wo2[k * 2001 + j], acc);
    out[r * 2001 + j] = acc > 0.f ? acc : 0.01f * acc;
}

// ===================== launcher ==========================================
extern "C" void kernel_launch(void* const* d_in, const int* in_sizes, int n_in,
                              void* d_out, int out_size, void* d_ws, size_t ws_size,
                              hipStream_t stream) {
    const float* x     = (const float*)d_in[0];
    const int*   ei    = (const int*)d_in[1];
    const float* ea    = (const float*)d_in[2];
    const int*   batch = (const int*)d_in[3];
    const float* W0 = (const float*)d_in[4];  const float* b0 = (const float*)d_in[5];
    const float* Wl1 = (const float*)d_in[6]; const float* bl1 = (const float*)d_in[7];
    const float* Wr1 = (const float*)d_in[8]; const float* br1 = (const float*)d_in[9];
    const float* We1 = (const float*)d_in[10]; const float* att1 = (const float*)d_in[11];
    const float* bias1 = (const float*)d_in[12];
    const float* Wl2 = (const float*)d_in[13]; const float* bl2 = (const float*)d_in[14];
    const float* Wr2 = (const float*)d_in[15]; const float* br2 = (const float*)d_in[16];
    const float* We2 = (const float*)d_in[17]; const float* att2 = (const float*)d_in[18];
    const float* bias2 = (const float*)d_in[19];
    const float* Wp = (const float*)d_in[20]; const float* bp = (const float*)d_in[21];
    const float* Wo1 = (const float*)d_in[22]; const float* bo1 = (const float*)d_in[23];
    const float* gamma = (const float*)d_in[24]; const float* beta = (const float*)d_in[25];
    const float* Wo2 = (const float*)d_in[26]; const float* bo2 = (const float*)d_in[27];
    float* out = (float*)d_out;

    char* p = (char*)d_ws;
    auto alloc = [&](size_t bytes) { char* r = p; p += (bytes + 255) & ~(size_t)255; return r; };
    const int MP = 30016;
    const int ET = 4688;
    __hip_bfloat16* xpad  = (__hip_bfloat16*)alloc((size_t)MP * 32 * 2);
    __hip_bfloat16* W2t   = (__hip_bfloat16*)alloc(512 * 256 * 2);
    __hip_bfloat16* Wpt   = (__hip_bfloat16*)alloc(256 * 256 * 2);
    ushort* Wef1 = (ushort*)alloc(256 * 64 * 2);
    ushort* Wef2 = (ushort*)alloc(256 * 64 * 2);
    ushort* Wct  = (ushort*)alloc(512 * 32 * 2);
    float* bc    = (float*)alloc(512 * 4);
    float* bcat2 = (float*)alloc(512 * 4);
    __hip_bfloat16* xlrb = (__hip_bfloat16*)alloc((size_t)MP * 512 * 2);
    __hip_bfloat16* h1b  = (__hip_bfloat16*)alloc((size_t)MP * 256 * 2);
    __hip_bfloat16* h2b  = (__hip_bfloat16*)alloc((size_t)MP * 256 * 2);
    ushort* ea_frag = (ushort*)alloc((size_t)ET * 4096 * 2);
    __hip_bfloat16* abuf = (__hip_bfloat16*)alloc((size_t)MP * 256 * 2);
    float* logit = (float*)alloc((size_t)EE * 4 * 4);
    int* deg    = (int*)alloc(NN * 4);
    int* cursor = (int*)alloc(NN * 4);
    int* partial= (int*)alloc(NN * 4);
    int* bsum   = (int*)alloc(256 * 4);
    int* start  = (int*)alloc((NN + 4) * 4);
    int* einv   = (int*)alloc((size_t)EE * 4);
    int* src_csr= (int*)alloc((size_t)EE * 4);
    int* dst_csr= (int*)alloc((size_t)EE * 4);
    unsigned* am = (unsigned*)alloc(BB * HC * 4);
    float* den  = (float*)alloc(BB * HC * 4);
    float* num  = (float*)alloc(BB * HC * 4);
    float* ybuf = (float*)alloc(BB * HC * 4);

    const int NB = (NN + 255) / 256;

    // ---- consolidated setup (packing + weight transforms + composition) ----
    SetupParams sp;
    sp.x = x; sp.W0 = W0; sp.b0 = b0; sp.Wl1 = Wl1; sp.Wr1 = Wr1;
    sp.Wl2 = Wl2; sp.Wr2 = Wr2; sp.Wp = Wp; sp.We1 = We1; sp.We2 = We2;
    sp.bl1 = bl1; sp.br1 = br1; sp.bl2 = bl2; sp.br2 = br2;
    sp.xpad = xpad; sp.W2t = W2t; sp.Wpt = Wpt;
    sp.Wef1 = Wef1; sp.Wef2 = Wef2; sp.Wct = Wct;
    sp.bcat2 = bcat2; sp.bc = bc; sp.deg = deg; sp.am = am;
    setup_all<<<4712, 256, 0, stream>>>(sp);

    // ---- CSR build ----
    hist_deg<<<(EE + 255) / 256, 256, 0, stream>>>(ei, deg);
    scan1<<<NB, 256, 0, stream>>>(deg, partial, bsum);
    scan3<<<NB + 1, 256, 0, stream>>>(partial, bsum, start, cursor);
    scatter_e<<<(EE + 255) / 256, 256, 0, stream>>>(ei, cursor, start, einv, src_csr, dst_csr);
    // coalesced-read / full-line scattered-write permute
    permute_ea_frag<<<9376, 256, 0, stream>>>(ea, einv, ea_frag);

    // ---- GAT layer 1 (init transform composed into weights: K=32) ----
    mfma_gemm<4><<<dim3(469, 2), 256, 0, stream>>>(
        (const ushort*)xpad, Wct, bc, nullptr, xlrb, NN, 512, 32);
    edge_fused<<<ET, 256, 0, stream>>>(ea_frag, Wef1, att1, src_csr, dst_csr,
                                       (const ushort*)xlrb, logit);
    aggregate_csr<<<7504, 256, 0, stream>>>(
        (const ushort*)xlrb, logit, src_csr, start, bias1, (ushort*)h1b);

    // ---- GAT layer 2 ----
    mfma_gemm<4><<<dim3(469, 2), 256, 0, stream>>>(
        (const ushort*)h1b, (const ushort*)W2t, bcat2, nullptr, xlrb, NN, 512, 256);
    edge_fused<<<ET, 256, 0, stream>>>(ea_frag, Wef2, att2, src_csr, dst_csr,
                                       (const ushort*)xlrb, logit);
    aggregate_csr<<<7504, 256, 0, stream>>>(
        (const ushort*)xlrb, logit, src_csr, start, bias2, (ushort*)h2b);

    // ---- attention pooling (chunk-parallel two-pass) ----
    mfma_gemm<4><<<dim3(469, 1), 256, 0, stream>>>(
        (const ushort*)h2b, (const ushort*)Wpt, bp, nullptr, abuf, NN, 256, 256);
    const int poolGrid = (NN + 63) / 64;
    pool_max<<<poolGrid, HC, 0, stream>>>(abuf, batch, am, den, num);
    pool_sums<<<poolGrid, HC, 0, stream>>>(abuf, h2b, batch, am, den, num);

    // ---- head MLP ----
    mlp_lin1<<<BB, HC, 0, stream>>>(num, den, Wo1, bo1, ybuf);
    bn_lin2<<<dim3(8, BB), 256, 0, stream>>>(ybuf, gamma, beta, Wo2, bo2, out);
}